// Round 4
// baseline (1007.513 us; speedup 1.0000x reference)
//
#include <hip/hip_runtime.h>
#include <math.h>

// DelayAndSum: out[b,t] = (1/S) * sum_s x[b, t+d_s, s] * (t+d_s < T)
// B=16, T=100000, S=128, d_s = rint(s*sin(ANGLE)/2) = (s+1)>>2 in [0,32].
//
// R4: aligned dual-slot formulation + XCD swizzle + 16-deep load pipeline.
// Lane L loads the ALIGNED float4 x[u, 4L..4L+3]. Sensors 4L,4L+1,4L+2 have
// delay L; sensor 4L+3 has delay L+1. So per row each lane makes TWO private
// LDS stores (no collisions, no cross-lane ops, no extra loads):
//   slot 2L   (A_L,    delay L  ): A = q.x+q.y+q.z   at  2L*STR     + r-L
//   slot 2L+1 (B_{L+1}, delay L+1): q.w              at (2L+1)*STR  + r-L-1
// Every slot s in [0,64) is populated (A_0..A_31 even, B_1..B_32 odd), all
// delay-rebased, so phase 2 is a uniform sum of 64 ds_read_b32 at ONE vgpr
// address + compile-time immediate offsets:
//   out[t0+tid] = (1/128) * sum_s P[s*STR + tid]
// Store bank = (L + r) & 31 -> all 32 banks per half-wave, conflict-free.
// Read bank  = tid & 31 per slot -> 2-way (free).
// LDS = 64*225*4 = 57600 B -> 2 blocks/CU (R3 proved occupancy 2 vs 5
// blocks is perf-neutral here, so we spend LDS on the lowest-halo tile).
// XCD swizzle: grid is 1D (16*nwgx, always %8==0); bijective chunk remap so
// adjacent tiles (sharing the 32-row halo) land on the same XCD's L2.
// Fallback: verified R2 kernel if the delay pattern ever differs.

#define SENS 128

// ---------------- fast path: 64 dual slots, aligned loads ----------------
#define FTT    224
#define FROWS  256
#define FSTR   225
#define FNSLOT 64

__global__ __launch_bounds__(256)
void das4_kernel(const float* __restrict__ x, float* __restrict__ out,
                 int T, int nwgx) {
    __shared__ float P[FNSLOT * FSTR];   // 57600 B

    // bijective XCD-aware swizzle (gridDim.x = 16*nwgx, multiple of 8)
    const int lin = blockIdx.x;
    const int q8  = (nwgx * 16) >> 3;
    const int wid = (lin & 7) * q8 + (lin >> 3);
    const int by  = wid / nwgx;            // batch b
    const int bx  = wid - by * nwgx;       // time tile

    const int tid = threadIdx.x;
    const int t0  = bx * FTT;
    const int L   = tid & 31;              // lane group / A-slot id
    const int rb  = tid >> 5;              // row-within-sweep (0..7)

    const float* __restrict__ xb = x + (size_t)by * (size_t)T * SENS + 4 * L;
    float* __restrict__ PA = P + (2 * L) * FSTR - L;          // A_L,    rebase -L
    float* __restrict__ PB = P + (2 * L + 1) * FSTR - L - 1;  // B_{L+1}, rebase -(L+1)

    if (t0 + FROWS <= T) {
        // hot path: 2 batches of 16 aligned float4 loads kept in flight
        #pragma unroll
        for (int bb = 0; bb < 2; ++bb) {
            float4 v[16];
            #pragma unroll
            for (int k = 0; k < 16; ++k) {
                const int r = bb * 128 + k * 8 + rb;
                v[k] = *(const float4*)(xb + (size_t)(t0 + r) * SENS);
            }
            #pragma unroll
            for (int k = 0; k < 16; ++k) {
                const int r = bb * 128 + k * 8 + rb;
                const float4 qv = v[k];
                const float A = qv.x + qv.y + qv.z;
                if (r >= L && r < L + FTT)      PA[r] = A;     // bank (L+r)&31
                if (r >= L + 1 && r < L + FSTR) PB[r] = qv.w;  // bank (L+r)&31
            }
        }
    } else {
        // tail tile: rows past T stay zero (this IS the validity mask)
        for (int i = tid; i < FNSLOT * FSTR; i += 256) P[i] = 0.0f;
        __syncthreads();
        for (int sw = 0; sw < FROWS / 8; ++sw) {
            const int r = sw * 8 + rb;
            const int u = t0 + r;
            if (u < T) {
                const float4 qv = *(const float4*)(xb + (size_t)u * SENS);
                const float A = qv.x + qv.y + qv.z;
                if (r >= L && r < L + FTT)      PA[r] = A;
                if (r >= L + 1 && r < L + FSTR) PB[r] = qv.w;
            }
        }
    }
    __syncthreads();

    // phase 2: uniform 64-slot sum, immediate offsets off one address
    const int t = t0 + tid;
    if (tid < FTT && t < T) {
        float acc = 0.0f;
        #pragma unroll
        for (int j = 0; j < FNSLOT; ++j)
            acc += P[j * FSTR + tid];
        out[(size_t)by * T + t] = acc * (1.0f / SENS);
    }
}

// ---------------- fallback: verified R2 kernel (64 partial slots) ----------------
#define TT   256
#define ROWS (TT + 32)
#define RSTR (ROWS + 1)
#define NSLOT 64

struct Tabs {
    int off[NSLOT];
    unsigned cm1, cm2, cm3;
};

__global__ __launch_bounds__(256)
void das2_kernel(const float* __restrict__ x, float* __restrict__ out,
                 Tabs tb, int T) {
    __shared__ float P[NSLOT * RSTR];

    const int tid = threadIdx.x;
    const int b   = blockIdx.y;
    const int t0  = blockIdx.x * TT;

    const int L = tid & 31;
    const bool c1 = (tb.cm1 >> L) & 1u;
    const bool c2 = (tb.cm2 >> L) & 1u;
    const bool c3 = (tb.cm3 >> L) & 1u;
    const int rb = tid >> 5;
    float* __restrict__ Pw = P + (2 * L) * RSTR;
    const float* __restrict__ xb = x + (size_t)b * (size_t)T * SENS + 4 * L;

    if (t0 + ROWS <= T) {
        #pragma unroll 4
        for (int sw = 0; sw < ROWS / 8; ++sw) {
            const int r = sw * 8 + rb;
            const float4 v = *(const float4*)(xb + (size_t)(t0 + r) * SENS);
            float a = v.x;
            a += c1 ? v.y : 0.0f;
            a += c2 ? v.z : 0.0f;
            a += c3 ? v.w : 0.0f;
            const float g = (c1 ? 0.0f : v.y) + (c2 ? 0.0f : v.z)
                          + (c3 ? 0.0f : v.w);
            Pw[r]        = a;
            Pw[RSTR + r] = g;
        }
    } else {
        for (int i = tid; i < NSLOT * RSTR; i += 256) P[i] = 0.0f;
        __syncthreads();
        for (int sw = 0; sw < ROWS / 8; ++sw) {
            const int r = sw * 8 + rb;
            const int u = t0 + r;
            if (u < T) {
                const float4 v = *(const float4*)(xb + (size_t)u * SENS);
                float a = v.x;
                a += c1 ? v.y : 0.0f;
                a += c2 ? v.z : 0.0f;
                a += c3 ? v.w : 0.0f;
                const float g = (c1 ? 0.0f : v.y) + (c2 ? 0.0f : v.z)
                              + (c3 ? 0.0f : v.w);
                Pw[r]        = a;
                Pw[RSTR + r] = g;
            }
        }
    }
    __syncthreads();

    const int t = t0 + tid;
    if (t < T) {
        float acc = 0.0f;
        #pragma unroll
        for (int j = 0; j < NSLOT; ++j)
            acc += P[tid + tb.off[j]];
        out[(size_t)b * T + t] = acc * (1.0f / SENS);
    }
}

extern "C" void kernel_launch(void* const* d_in, const int* in_sizes, int n_in,
                              void* d_out, int out_size, void* d_ws, size_t ws_size,
                              hipStream_t stream) {
    const float* x = (const float*)d_in[0];
    float* out = (float*)d_out;

    const int B = 16;
    const int T = in_sizes[0] / (B * SENS);   // 100000

    // Replicate numpy's delay computation exactly (libm sin, rint half-even).
    int d[SENS];
    const double sv = sin(0.5235987755982988);
    for (int s = 0; s < SENS; ++s)
        d[s] = (int)rint((double)s * sv / 2.0);

    // Fast path requires d[4L..4L+2] == L and d[4L+3] == L+1 for all L.
    bool fast = true;
    for (int L = 0; L < 32; ++L) {
        if (d[4 * L + 0] != L || d[4 * L + 1] != L ||
            d[4 * L + 2] != L || d[4 * L + 3] != L + 1) { fast = false; break; }
    }

    if (fast) {
        const int nwgx = (T + FTT - 1) / FTT;          // 447
        dim3 grid(nwgx * B);                           // 7152, %8 == 0
        das4_kernel<<<grid, dim3(256), 0, stream>>>(x, out, T, nwgx);
    } else {
        Tabs tb;
        tb.cm1 = tb.cm2 = tb.cm3 = 0u;
        for (int L = 0; L < 32; ++L) {
            const int d0 = d[4 * L + 0], d1 = d[4 * L + 1];
            const int d2 = d[4 * L + 2], d3 = d[4 * L + 3];
            if (d1 == d0) tb.cm1 |= 1u << L;
            if (d2 == d0) tb.cm2 |= 1u << L;
            if (d3 == d0) tb.cm3 |= 1u << L;
            tb.off[2 * L + 0] = (2 * L + 0) * RSTR + d0;
            tb.off[2 * L + 1] = (2 * L + 1) * RSTR + d3;
        }
        dim3 grid((T + TT - 1) / TT, B);
        das2_kernel<<<grid, dim3(256), 0, stream>>>(x, out, tb, T);
    }
}